// Round 12
// baseline (626.450 us; speedup 1.0000x reference)
//
#include <hip/hip_runtime.h>
#include <stdint.h>

#define T_DIM 512
#define B_DIM 128
#define I_DIM 1024
#define N_DIM 1024
#define NB (N_DIM * B_DIM)     // 131072
#define ROWB 4096              // combined W row bytes: I * (hi+lo f16) = 4 KB

#define DECAY 0.9f
#define THRESH 1.0f

typedef _Float16 f16;
typedef _Float16 f16x8 __attribute__((ext_vector_type(8)));
typedef float f32x4 __attribute__((ext_vector_type(4)));

#define MFMA16 __builtin_amdgcn_mfma_f32_16x16x32_f16

// -------------------------------------------------------------------------
// Split fp32 W -> combined f16 hi/lo layout: [row][kc=0..127][hl][8 f16].
// (A-side layout unchanged — staged via global_load_lds in the GEMM.)
// -------------------------------------------------------------------------
__global__ __launch_bounds__(256) void split_w_kernel(
    const float* __restrict__ W, f16* __restrict__ Ws)
{
    int gid = blockIdx.x * 256 + threadIdx.x;       // N*I/8 kchunks
    int kc  = gid & 127;
    int row = gid >> 7;
    const float* src = W + (size_t)row * I_DIM + kc * 8;
    f16* dst = Ws + (size_t)row * 2048 + kc * 16;
    float v[8];
    *(float4*)&v[0] = *(const float4*)src;
    *(float4*)&v[4] = *(const float4*)(src + 4);
    f16 hi[8], lo[8];
    #pragma unroll
    for (int j = 0; j < 8; ++j) {
        hi[j] = (f16)v[j];
        lo[j] = (f16)(v[j] - (float)hi[j]);
    }
    *(f16x8*)dst       = *(const f16x8*)hi;
    *(f16x8*)(dst + 8) = *(const f16x8*)lo;
}

// -------------------------------------------------------------------------
// Split X -> FRAGMENT-READY layout:
//   Xc2[t'][kt (0..31)][sg (0..7 = octet*2+hl)][col (0..127)][8 f16]
// A wave's B-fragment (16 cols x 1 granule) is 256B contiguous -> B loads
// go straight to VGPRs, perfectly coalesced; B never touches LDS.
// Block: 256 thr handles (t', 4 kt). LDS transpose for coalesced in+out.
// -------------------------------------------------------------------------
__global__ __launch_bounds__(256) void split_x2_kernel(
    const float* __restrict__ X, f16* __restrict__ Xc2, int t0)
{
    __shared__ f16 sgm[32768];   // [4 ktl][8 sg][128 col][8 f16] = 64 KB

    const int bid = blockIdx.x, tid = threadIdx.x;
    const int tp = bid >> 3;                 // chunk-local t'
    const int t  = t0 + tp;
    const int ktbase = (bid & 7) * 4;

    // coalesced read: thread = (col, half); 64 consecutive floats (2 kt)
    const int col = tid >> 1, h = tid & 1;
    const float* src = X + ((size_t)col * T_DIM + t) * I_DIM + ktbase * 32 + h * 64;
    float4 v4[16];
    #pragma unroll
    for (int i = 0; i < 16; ++i) v4[i] = *(const float4*)(src + i * 4);

    #pragma unroll
    for (int o = 0; o < 8; ++o) {            // octet within my 64 floats
        float f[8];
        *(float4*)&f[0] = v4[o * 2];
        *(float4*)&f[4] = v4[o * 2 + 1];
        f16 hi[8], lo[8];
        #pragma unroll
        for (int j = 0; j < 8; ++j) {
            hi[j] = (f16)f[j];
            lo[j] = (f16)(f[j] - (float)hi[j]);
        }
        const int ktl = h * 2 + (o >> 2);    // local kt 0..3
        const int oo  = o & 3;               // octet within kt
        *(f16x8*)&sgm[(((ktl * 8 + oo * 2 + 0) * 128) + col) * 8] = *(f16x8*)hi;
        *(f16x8*)&sgm[(((ktl * 8 + oo * 2 + 1) * 128) + col) * 8] = *(f16x8*)lo;
    }
    __syncthreads();

    // coalesced write: thread = (ktl, sg, colgrp of 16) -> 256B contiguous
    const int ktl = tid >> 6, sgi = (tid >> 3) & 7, cg = tid & 7;
    f16* dst = Xc2 + ((size_t)((tp * 32 + ktbase + ktl) * 8 + sgi) * 128 + cg * 16) * 8;
    const f16* ls = &sgm[((ktl * 8 + sgi) * 128 + cg * 16) * 8];
    #pragma unroll
    for (int g = 0; g < 16; ++g)
        *(f16x8*)(dst + g * 8) = *(const f16x8*)(ls + g * 8);
}

// -------------------------------------------------------------------------
// GEMM via fp16-split 3xMFMA. Round-3 geometry (128n x 128b / block / t,
// 4 waves 64x64, BK=32, 2 blocks/CU) with B REMOVED FROM LDS:
//   A (W combined): global_load_lds dbuf, 2 x 16KB (linear dest, inv-XOR src)
//   B (Xc2 frag-ready): direct global->VGPR, 8 imm-offset dwordx4 per K-tile,
//     double-banked registers, prefetched 1 tile ahead.
// Per K-tile: s_barrier / stage A(kt+1) + load B(kt+1)->regs / vmcnt(12)
//   [= A(kt),B(kt) done] / s_barrier / 8 ds_read A + 48 MFMA term-outer.
// LDS traffic per block-K-tile: 16KB write + 32KB read (was 32+64).
// -------------------------------------------------------------------------
__global__ __launch_bounds__(256, 2) void spk_gemm_kernel(
    const uint8_t* __restrict__ Wsb,   // combined W [N][kc][hl][8]
    const uint8_t* __restrict__ Xc2b,  // frag-ready Xc2 (512KB per t')
    float* __restrict__ C, int t0)
{
    __shared__ __align__(16) uint8_t lds[32768];   // 2 x A 16KB

    const int tid  = threadIdx.x;
    const int wave = tid >> 6, lane = tid & 63;

    // bijective chunked XCD swizzle: same-t blocks colocate on one XCD
    const int nwg = gridDim.x;
    const int q = nwg >> 3, r = nwg & 7;
    const int xcd = blockIdx.x & 7, idx = blockIdx.x >> 3;
    const int wg = (xcd < r ? xcd * (q + 1) : r * (q + 1) + (xcd - r) * q) + idx;
    const int n0 = (wg & 7) << 7;
    const int tp = wg >> 3;

    // A staging: 4 granules (16B)/thread; dest linear, src inverse-XOR swizzled
    const uint8_t* srcA[4];
    #pragma unroll
    for (int c = 0; c < 4; ++c) {
        int G = c * 256 + tid;           // 0..1023
        int rr = G >> 3, gg = G & 7;
        srcA[c] = Wsb + (size_t)(n0 + rr) * ROWB + ((gg ^ (rr & 7)) << 4);
    }

    const int wr = ((wave >> 1) << 6);   // n-offset 0/64
    const int wc = ((wave & 1) << 6);    // b-offset 0/64
    const int l15 = lane & 15, kcg = lane >> 4, l7 = l15 & 7;

    // A fragment LDS offsets (same XOR scheme as r3)
    int aoffH[4], aoffL[4];
    #pragma unroll
    for (int m = 0; m < 4; ++m) {
        int ra = wr + m * 16 + l15;
        aoffH[m] = ra * 128 + ((((kcg << 1) | 0) ^ l7) << 4);
        aoffL[m] = ra * 128 + ((((kcg << 1) | 1) ^ l7) << 4);
    }

    // B per-lane base: sg = kcg*2+hl plane (2KB each), col = wc+nf*16+l15
    const uint8_t* bB = Xc2b + (size_t)tp * 524288
                        + (kcg * 2) * 2048 + (wc + l15) * 16;

    f32x4 acc[4][4];
    #pragma unroll
    for (int m = 0; m < 4; ++m)
        #pragma unroll
        for (int n = 0; n < 4; ++n) acc[m][n] = (f32x4){0.f, 0.f, 0.f, 0.f};

#define STAGE_A(KT1, QB) do {                                                 \
    _Pragma("unroll")                                                         \
    for (int c_ = 0; c_ < 4; ++c_)                                            \
        __builtin_amdgcn_global_load_lds(                                     \
            (const __attribute__((address_space(1))) uint8_t*)(srcA[c_] + (KT1) * 128), \
            (__attribute__((address_space(3))) uint8_t*)&lds[(QB) + c_ * 4096 + (wave << 10)], \
            16, 0, 0);                                                        \
} while (0)

#define LOAD_B(KT1, BH, BL) do {                                              \
    const uint8_t* pb_ = bB + (size_t)(KT1) * 16384;                          \
    _Pragma("unroll")                                                         \
    for (int nf_ = 0; nf_ < 4; ++nf_) {                                       \
        BH[nf_] = *(const f16x8*)(pb_ + nf_ * 256);                           \
        BL[nf_] = *(const f16x8*)(pb_ + nf_ * 256 + 2048);                    \
    }                                                                         \
} while (0)

#define COMPUTE(QB, BH, BL) do {                                              \
    const uint8_t* bp_ = &lds[(QB)];                                          \
    f16x8 Ah_[4], Al_[4];                                                     \
    _Pragma("unroll")                                                         \
    for (int m_ = 0; m_ < 4; ++m_) {                                          \
        Ah_[m_] = *(const f16x8*)&bp_[aoffH[m_]];                             \
        Al_[m_] = *(const f16x8*)&bp_[aoffL[m_]];                             \
    }                                                                         \
    __builtin_amdgcn_s_setprio(1);                                            \
    _Pragma("unroll")                                                         \
    for (int m_ = 0; m_ < 4; ++m_)                                            \
        _Pragma("unroll")                                                     \
        for (int n_ = 0; n_ < 4; ++n_)                                        \
            acc[m_][n_] = MFMA16(Ah_[m_], BH[n_], acc[m_][n_], 0, 0, 0);      \
    _Pragma("unroll")                                                         \
    for (int m_ = 0; m_ < 4; ++m_)                                            \
        _Pragma("unroll")                                                     \
        for (int n_ = 0; n_ < 4; ++n_)                                        \
            acc[m_][n_] = MFMA16(Ah_[m_], BL[n_], acc[m_][n_], 0, 0, 0);      \
    _Pragma("unroll")                                                         \
    for (int m_ = 0; m_ < 4; ++m_)                                            \
        _Pragma("unroll")                                                     \
        for (int n_ = 0; n_ < 4; ++n_)                                        \
            acc[m_][n_] = MFMA16(Al_[m_], BH[n_], acc[m_][n_], 0, 0, 0);      \
    __builtin_amdgcn_s_setprio(0);                                            \
} while (0)

// steady body for tile KT (issues KT+1): outstanding before = A(KT)4+B(KT)8;
// after issue = 24; vmcnt(12) => tile KT fully resident/loaded.
#define BODY(KT, QBN, QBC, BHL_N0, BHL_N1, BHL_C0, BHL_C1) do {               \
    __builtin_amdgcn_s_barrier();                                             \
    STAGE_A((KT) + 1, QBN);                                                   \
    LOAD_B((KT) + 1, BHL_N0, BHL_N1);                                         \
    asm volatile("s_waitcnt vmcnt(12)" ::: "memory");                         \
    __builtin_amdgcn_s_barrier();                                             \
    __builtin_amdgcn_sched_barrier(0);                                        \
    COMPUTE(QBC, BHL_C0, BHL_C1);                                             \
} while (0)

    f16x8 B0h[4], B0l[4], B1h[4], B1l[4];

    // prologue: tile 0 -> buf0 + bank0
    STAGE_A(0, 0);
    LOAD_B(0, B0h, B0l);

    for (int kt = 0; kt < 30; kt += 2) {
        BODY(kt,     16384, 0,     B1h, B1l, B0h, B0l);
        BODY(kt + 1, 0,     16384, B0h, B0l, B1h, B1l);
    }
    BODY(30, 16384, 0, B1h, B1l, B0h, B0l);
    // tail: tile 31 (no further issues)
    __builtin_amdgcn_s_barrier();
    asm volatile("s_waitcnt vmcnt(0)" ::: "memory");
    __builtin_amdgcn_s_barrier();
    __builtin_amdgcn_sched_barrier(0);
    COMPUTE(16384, B1h, B1l);

    // epilogue: C[t'][n][b]; C/D map col=lane&15, row=(lane>>4)*4+j
    float* cp = C + (size_t)tp * NB;
    const int rg = (lane >> 4) << 2;
    #pragma unroll
    for (int m = 0; m < 4; ++m) {
        int nrow = n0 + wr + m * 16 + rg;
        #pragma unroll
        for (int n = 0; n < 4; ++n) {
            int col = wc + n * 16 + l15;
            #pragma unroll
            for (int j = 0; j < 4; ++j)
                cp[(size_t)(nrow + j) * B_DIM + col] = acc[m][n][j];
        }
    }
}

// -------------------------------------------------------------------------
// Sequential LIF scan per (n,b); state carried across chunk launches.
// -------------------------------------------------------------------------
__global__ __launch_bounds__(256) void spk_scan_kernel(
    const float* __restrict__ cur,   // [tc, NB]
    float* __restrict__ mp_state,    // [NB]
    float* __restrict__ out,         // [NB]
    int tc, int first)
{
    const int nb = blockIdx.x * 256 + threadIdx.x;
    float mp, cnt;
    if (first) { mp = 0.0f; cnt = 0.0f; }
    else       { mp = mp_state[nb]; cnt = out[nb]; }

    const float* p = cur + nb;
    #pragma unroll 8
    for (int t = 0; t < tc; ++t) {
        float c = p[(size_t)t * NB];
        mp = __fadd_rn(__fmul_rn(DECAY, mp), c);
        if (mp >= THRESH) { cnt += 1.0f; mp = 0.0f; }
    }
    mp_state[nb] = mp;
    out[nb] = cnt;
}

extern "C" void kernel_launch(void* const* d_in, const int* in_sizes, int n_in,
                              void* d_out, int out_size, void* d_ws, size_t ws_size,
                              hipStream_t stream) {
    const float* x = (const float*)d_in[0];   // [B, T, I]
    const float* w = (const float*)d_in[1];   // [N, I]
    float* out = (float*)d_out;               // [N, B]

    uint8_t* ws = (uint8_t*)d_ws;
    float* mp  = (float*)ws;                                 // 512 KB
    f16*   Wsp = (f16*)(ws + 524288);                        // 4 MB combined W
    uint8_t* rest = ws + 524288 + 4194304;
    size_t rem = ws_size - 524288 - 4194304;

    // per-t footprint: Xc2 512KB + cur 512KB = 1 MB
    int Tc = (int)(rem / (size_t)(128 * ROWB + NB * 4));
    if (Tc > T_DIM) Tc = T_DIM;
    if (Tc < 1) Tc = 1;

    f16*   Xcp = (f16*)rest;                                 // Tc * 512 KB
    float* cur = (float*)(rest + (size_t)Tc * 128 * ROWB);   // Tc * 512 KB

    split_w_kernel<<<(N_DIM * I_DIM / 8) / 256, 256, 0, stream>>>(w, Wsp);

    int first = 1;
    for (int t0 = 0; t0 < T_DIM; ) {
        int tc = T_DIM - t0;
        if (tc > Tc) tc = Tc;

        split_x2_kernel<<<tc * 8, 256, 0, stream>>>(x, Xcp, t0);
        spk_gemm_kernel<<<tc * 8, 256, 0, stream>>>(
            (const uint8_t*)Wsp, (const uint8_t*)Xcp, cur, t0);
        spk_scan_kernel<<<NB / 256, 256, 0, stream>>>(cur, mp, out, tc, first);

        first = 0;
        t0 += tc;
    }
}

// Round 13
// 518.888 us; speedup vs baseline: 1.2073x; 1.2073x over previous
//
#include <hip/hip_runtime.h>
#include <stdint.h>

#define T_DIM 512
#define B_DIM 128
#define I_DIM 1024
#define N_DIM 1024
#define NB (N_DIM * B_DIM)     // 131072
#define ROWB 4096              // bytes per combined row: I * (hi+lo f16) = 4 KB

#define DECAY 0.9f
#define THRESH 1.0f

typedef _Float16 f16;
typedef _Float16 f16x8 __attribute__((ext_vector_type(8)));
typedef float f32x4 __attribute__((ext_vector_type(4)));

#define MFMA16 __builtin_amdgcn_mfma_f32_16x16x32_f16

// -------------------------------------------------------------------------
// Split fp32 -> combined f16 hi/lo layout: dst[row][kc=0..127][hl][8 f16].
// -------------------------------------------------------------------------
__global__ __launch_bounds__(256) void split_w_kernel(
    const float* __restrict__ W, f16* __restrict__ Ws)
{
    int gid = blockIdx.x * 256 + threadIdx.x;       // N*I/8 kchunks
    int kc  = gid & 127;
    int row = gid >> 7;
    const float* src = W + (size_t)row * I_DIM + kc * 8;
    f16* dst = Ws + (size_t)row * 2048 + kc * 16;
    float v[8];
    *(float4*)&v[0] = *(const float4*)src;
    *(float4*)&v[4] = *(const float4*)(src + 4);
    f16 hi[8], lo[8];
    #pragma unroll
    for (int j = 0; j < 8; ++j) {
        hi[j] = (f16)v[j];
        lo[j] = (f16)(v[j] - (float)hi[j]);
    }
    *(f16x8*)dst       = *(const f16x8*)hi;
    *(f16x8*)(dst + 8) = *(const f16x8*)lo;
}

// X chunk: rows indexed [t'][b] (t-major)
__global__ __launch_bounds__(256) void split_x_kernel(
    const float* __restrict__ X, f16* __restrict__ Xc, int t0)
{
    int gid = blockIdx.x * 256 + threadIdx.x;       // tc*128*128 kchunks
    int kc = gid & 127;
    int b  = (gid >> 7) & 127;
    int tp = gid >> 14;
    const float* src = X + ((size_t)b * T_DIM + (t0 + tp)) * I_DIM + kc * 8;
    f16* dst = Xc + ((size_t)tp * 128 + b) * 2048 + kc * 16;
    float v[8];
    *(float4*)&v[0] = *(const float4*)src;
    *(float4*)&v[4] = *(const float4*)(src + 4);
    f16 hi[8], lo[8];
    #pragma unroll
    for (int j = 0; j < 8; ++j) {
        hi[j] = (f16)v[j];
        lo[j] = (f16)(v[j] - (float)hi[j]);
    }
    *(f16x8*)dst       = *(const f16x8*)hi;
    *(f16x8*)(dst + 8) = *(const f16x8*)lo;
}

// -------------------------------------------------------------------------
// GEMM via fp16-split 3xMFMA — round-3 structure verbatim (128n x 128b tile
// per block per t, 4 waves 64x64, BK=32, 2x32KB LDS dbuf, 2 blocks/CU, ONE
// __syncthreads per K-step with next-tile stage in flight across compute)
// PLUS anti-phase-lock changes:
//   (1) entry stagger: sleep (bid%5)*~450cyc so the CU's 2 blocks offset;
//   (2) s_setprio(1) around the MFMA cluster: a computing block monopolizes
//       issue, pushing its partner into the LDS-read role -> alternation;
//   (3) term-outer MFMA order: 16 independent MFMAs between acc reuses so
//       the solo compute phase has no dependent-chain stalls.
// Goal: overlap the CU's ~1536cyc LDS service with the ~1862cyc MFMA phase
// instead of serializing them (measured wall 3456 ~= their sum).
// -------------------------------------------------------------------------
__global__ __launch_bounds__(256, 2) void spk_gemm_kernel(
    const uint8_t* __restrict__ Wsb,   // combined W  [N][kc][hl][8]
    const uint8_t* __restrict__ Xcb,   // combined Xc [t'*128+b][kc][hl][8]
    float* __restrict__ C, int tc)
{
    __shared__ __align__(16) uint8_t lds[65536];   // 2 x (A 16K | B 16K)

    const int tid  = threadIdx.x;
    const int wave = tid >> 6, lane = tid & 63;

    // entry stagger: 0/450/900/1350/1800 cyc by bid%5 (coprime to pairing
    // strides 1/2/256/512 -> co-resident blocks almost surely offset)
    {
        const int stag = blockIdx.x % 5;
        for (int i = 0; i < stag; ++i) __builtin_amdgcn_s_sleep(7);
    }

    // bijective chunked XCD swizzle: same-t blocks colocate on one XCD
    const int nwg = gridDim.x;
    const int q = nwg >> 3, r = nwg & 7;
    const int xcd = blockIdx.x & 7, idx = blockIdx.x >> 3;
    const int wg = (xcd < r ? xcd * (q + 1) : r * (q + 1) + (xcd - r) * q) + idx;
    const int n0 = (wg & 7) << 7;
    const int tp = wg >> 3;

    // staging: 8 granules (16B) per thread; LDS dest linear (granule G*16),
    // source granule XOR-swizzled within each 128B row-chunk.
    const uint8_t* srcp[8];
    #pragma unroll
    for (int c = 0; c < 8; ++c) {
        int Gall = (wave * 8 + c) * 64 + lane;
        int G  = Gall & 1023;
        int rr = G >> 3, gg = G & 7;
        int xofs = ((gg ^ (rr & 7)) << 4);
        if (Gall < 1024)
            srcp[c] = Wsb + (size_t)(n0 + rr) * ROWB + xofs;
        else
            srcp[c] = Xcb + ((size_t)tp * 128 + rr) * ROWB + xofs;
    }

    // fragment LDS byte offsets within a buffer (constant across K-steps)
    const int wr = ((wave >> 1) << 6);   // n-offset 0/64
    const int wc = ((wave & 1) << 6);    // b-offset 0/64
    const int l15 = lane & 15, kcg = lane >> 4, l7 = l15 & 7;
    int aoffH[4], aoffL[4], boffH[4], boffL[4];
    #pragma unroll
    for (int m = 0; m < 4; ++m) {
        int ra = wr + m * 16 + l15;
        aoffH[m] = ra * 128 + ((((kcg << 1) | 0) ^ l7) << 4);
        aoffL[m] = ra * 128 + ((((kcg << 1) | 1) ^ l7) << 4);
        int rb = wc + m * 16 + l15;
        boffH[m] = 16384 + rb * 128 + ((((kcg << 1) | 0) ^ l7) << 4);
        boffL[m] = 16384 + rb * 128 + ((((kcg << 1) | 1) ^ l7) << 4);
    }

    f32x4 acc[4][4];
    #pragma unroll
    for (int m = 0; m < 4; ++m)
        #pragma unroll
        for (int n = 0; n < 4; ++n) acc[m][n] = (f32x4){0.f, 0.f, 0.f, 0.f};

    // prologue: stage tile 0 into buffer 0
    #pragma unroll
    for (int c = 0; c < 8; ++c)
        __builtin_amdgcn_global_load_lds(
            (const __attribute__((address_space(1))) uint8_t*)srcp[c],
            (__attribute__((address_space(3))) uint8_t*)&lds[(wave * 8 + c) << 10],
            16, 0, 0);

    int cur = 0;
    for (int ks = 0; ks < 32; ++ks) {
        __syncthreads();   // drains vmcnt(0): buf[cur] ready; WAR-safe for stage below

        // stage NEXT K-step into the other buffer (in flight across the MFMAs)
        if (ks + 1 < 32) {
            const int nb = (cur ^ 1) << 15;
            #pragma unroll
            for (int c = 0; c < 8; ++c)
                __builtin_amdgcn_global_load_lds(
                    (const __attribute__((address_space(1))) uint8_t*)(srcp[c] + (ks + 1) * 128),
                    (__attribute__((address_space(3))) uint8_t*)&lds[nb + ((wave * 8 + c) << 10)],
                    16, 0, 0);
        }

        const uint8_t* bp = &lds[cur << 15];
        f16x8 Ah[4], Al[4], Bh[4], Bl[4];
        #pragma unroll
        for (int m = 0; m < 4; ++m) {
            Ah[m] = *(const f16x8*)&bp[aoffH[m]];
            Al[m] = *(const f16x8*)&bp[aoffL[m]];
        }
        #pragma unroll
        for (int n = 0; n < 4; ++n) {
            Bh[n] = *(const f16x8*)&bp[boffH[n]];
            Bl[n] = *(const f16x8*)&bp[boffL[n]];
        }

        // 48 MFMAs, term-outer (16 independent between acc reuses), prio-1
        __builtin_amdgcn_s_setprio(1);
        #pragma unroll
        for (int m = 0; m < 4; ++m)
            #pragma unroll
            for (int n = 0; n < 4; ++n)
                acc[m][n] = MFMA16(Ah[m], Bh[n], acc[m][n], 0, 0, 0);
        #pragma unroll
        for (int m = 0; m < 4; ++m)
            #pragma unroll
            for (int n = 0; n < 4; ++n)
                acc[m][n] = MFMA16(Ah[m], Bl[n], acc[m][n], 0, 0, 0);
        #pragma unroll
        for (int m = 0; m < 4; ++m)
            #pragma unroll
            for (int n = 0; n < 4; ++n)
                acc[m][n] = MFMA16(Al[m], Bh[n], acc[m][n], 0, 0, 0);
        __builtin_amdgcn_s_setprio(0);
        cur ^= 1;
    }

    // epilogue: C[t'][n][b]; C/D map col=lane&15, row=(lane>>4)*4+j
    float* cp = C + (size_t)tp * NB;
    const int rg = (lane >> 4) << 2;
    #pragma unroll
    for (int m = 0; m < 4; ++m) {
        int nrow = n0 + wr + m * 16 + rg;
        #pragma unroll
        for (int n = 0; n < 4; ++n) {
            int col = wc + n * 16 + l15;
            #pragma unroll
            for (int j = 0; j < 4; ++j)
                cp[(size_t)(nrow + j) * B_DIM + col] = acc[m][n][j];
        }
    }
}

// -------------------------------------------------------------------------
// Sequential LIF scan per (n,b); state carried across chunk launches.
// -------------------------------------------------------------------------
__global__ __launch_bounds__(256) void spk_scan_kernel(
    const float* __restrict__ cur,   // [tc, NB]
    float* __restrict__ mp_state,    // [NB]
    float* __restrict__ out,         // [NB]
    int tc, int first)
{
    const int nb = blockIdx.x * 256 + threadIdx.x;
    float mp, cnt;
    if (first) { mp = 0.0f; cnt = 0.0f; }
    else       { mp = mp_state[nb]; cnt = out[nb]; }

    const float* p = cur + nb;
    #pragma unroll 8
    for (int t = 0; t < tc; ++t) {
        float c = p[(size_t)t * NB];
        mp = __fadd_rn(__fmul_rn(DECAY, mp), c);
        if (mp >= THRESH) { cnt += 1.0f; mp = 0.0f; }
    }
    mp_state[nb] = mp;
    out[nb] = cnt;
}

extern "C" void kernel_launch(void* const* d_in, const int* in_sizes, int n_in,
                              void* d_out, int out_size, void* d_ws, size_t ws_size,
                              hipStream_t stream) {
    const float* x = (const float*)d_in[0];   // [B, T, I]
    const float* w = (const float*)d_in[1];   // [N, I]
    float* out = (float*)d_out;               // [N, B]

    uint8_t* ws = (uint8_t*)d_ws;
    float* mp  = (float*)ws;                                 // 512 KB
    f16*   Wsp = (f16*)(ws + 524288);                        // 4 MB combined W
    uint8_t* rest = ws + 524288 + 4194304;
    size_t rem = ws_size - 524288 - 4194304;

    // per-t footprint: Xc row block 512KB + cur 512KB = 1 MB
    int Tc = (int)(rem / (size_t)(128 * ROWB + NB * 4));
    if (Tc > T_DIM) Tc = T_DIM;
    if (Tc < 1) Tc = 1;

    f16*   Xcp = (f16*)rest;                                 // Tc * 512 KB
    float* cur = (float*)(rest + (size_t)Tc * 128 * ROWB);   // Tc * 512 KB

    split_w_kernel<<<(N_DIM * I_DIM / 8) / 256, 256, 0, stream>>>(w, Wsp);

    int first = 1;
    for (int t0 = 0; t0 < T_DIM; ) {
        int tc = T_DIM - t0;
        if (tc > Tc) tc = Tc;

        split_x_kernel<<<tc * 64, 256, 0, stream>>>(x, Xcp, t0);
        spk_gemm_kernel<<<tc * 8, 256, 0, stream>>>(
            (const uint8_t*)Wsp, (const uint8_t*)Xcp, cur, tc);
        spk_scan_kernel<<<NB / 256, 256, 0, stream>>>(cur, mp, out, tc, first);

        first = 0;
        t0 += tc;
    }
}